// Round 2
// baseline (14300.941 us; speedup 1.0000x reference)
//
#include <hip/hip_runtime.h>
#include <hip/hip_bf16.h>

#define NN 40000      // nodes
#define NE 150000     // edges per type
#define HF 512        // H*D
#define NHEAD 4

typedef __bf16 bf16x8 __attribute__((ext_vector_type(8)));
typedef float floatx4 __attribute__((ext_vector_type(4)));
typedef __hip_bfloat16 bf16;

__device__ __forceinline__ float bf2f(bf16 v) { return __bfloat162float(v); }

// monotone order-preserving float<->uint encoding for atomicMax on floats
__device__ __forceinline__ unsigned enc_f(float f) {
    unsigned u = __float_as_uint(f);
    return (u & 0x80000000u) ? ~u : (u | 0x80000000u);
}
__device__ __forceinline__ float dec_f(unsigned u) {
    u = (u & 0x80000000u) ? (u ^ 0x80000000u) : ~u;
    return __uint_as_float(u);
}

// ---------------- cast fp32 -> bf16, elementwise ----------------
__global__ void cast_k(const float* __restrict__ in, bf16* __restrict__ out, int n) {
    int i = (blockIdx.x * blockDim.x + threadIdx.x) * 4;
    if (i + 3 < n) {
        float4 v = *(const float4*)(in + i);
        out[i + 0] = __float2bfloat16(v.x);
        out[i + 1] = __float2bfloat16(v.y);
        out[i + 2] = __float2bfloat16(v.z);
        out[i + 3] = __float2bfloat16(v.w);
    } else {
        for (int j = i; j < n; j++) out[j] = __float2bfloat16(in[j]);
    }
}

// ---------------- transpose+cast: WT[n*K+k] = bf16(W[k*N+n]) ----------------
__global__ void transpose_k(const float* __restrict__ W, bf16* __restrict__ WT,
                            int K, int Nn) {
    __shared__ float tile[32][33];
    int n0 = blockIdx.x * 32, k0 = blockIdx.y * 32;
    int tx = threadIdx.x, ty = threadIdx.y;
    int n = n0 + tx, k = k0 + ty;
    if (n < Nn && k < K) tile[ty][tx] = W[(size_t)k * Nn + n];
    __syncthreads();
    int nn = n0 + ty, kk = k0 + tx;
    if (nn < Nn && kk < K) WT[(size_t)nn * K + kk] = __float2bfloat16(tile[tx][ty]);
}

// ---------------- GEMM: C[M,Nn] = A[M,K] * BT[Nn,K]^T ----------------
// A,BT bf16 row-major. TOUT = float; optional fp32 bias.
template <bool HAS_BIAS>
__global__ __launch_bounds__(256) void gemm_k(const bf16* __restrict__ A,
                                              const bf16* __restrict__ BT,
                                              float* __restrict__ C,
                                              const float* __restrict__ bias,
                                              int M, int Nn, int K) {
    __shared__ __align__(16) unsigned short As[64][40];
    __shared__ __align__(16) unsigned short Bs[64][40];
    const int m0 = blockIdx.x * 64;
    const int n0 = blockIdx.y * 64;
    const int t = threadIdx.x;
    const int lane = t & 63;
    const int wave = t >> 6;
    const int wm = wave >> 1, wn = wave & 1;
    const int q = lane >> 4, r = lane & 15;
    const int srow = t >> 2;
    const int scol = (t & 3) * 8;
    const bool a_ok = (m0 + srow) < M;
    const bool b_ok = (n0 + srow) < Nn;
    const unsigned short* Arow = (const unsigned short*)A + (size_t)(m0 + srow) * K + scol;
    const unsigned short* Brow = (const unsigned short*)BT + (size_t)(n0 + srow) * K + scol;

    floatx4 acc[2][2] = {};
    for (int k0 = 0; k0 < K; k0 += 32) {
        uint4 av = make_uint4(0, 0, 0, 0), bv = make_uint4(0, 0, 0, 0);
        if (a_ok) av = *(const uint4*)(Arow + k0);
        if (b_ok) bv = *(const uint4*)(Brow + k0);
        *(uint4*)&As[srow][scol] = av;
        *(uint4*)&Bs[srow][scol] = bv;
        __syncthreads();
        bf16x8 a0 = *(const bf16x8*)&As[wm * 32 + r][q * 8];
        bf16x8 a1 = *(const bf16x8*)&As[wm * 32 + 16 + r][q * 8];
        bf16x8 b0 = *(const bf16x8*)&Bs[wn * 32 + r][q * 8];
        bf16x8 b1 = *(const bf16x8*)&Bs[wn * 32 + 16 + r][q * 8];
        acc[0][0] = __builtin_amdgcn_mfma_f32_16x16x32_bf16(a0, b0, acc[0][0], 0, 0, 0);
        acc[0][1] = __builtin_amdgcn_mfma_f32_16x16x32_bf16(a0, b1, acc[0][1], 0, 0, 0);
        acc[1][0] = __builtin_amdgcn_mfma_f32_16x16x32_bf16(a1, b0, acc[1][0], 0, 0, 0);
        acc[1][1] = __builtin_amdgcn_mfma_f32_16x16x32_bf16(a1, b1, acc[1][1], 0, 0, 0);
        __syncthreads();
    }
#pragma unroll
    for (int i = 0; i < 2; i++)
#pragma unroll
        for (int j = 0; j < 2; j++)
#pragma unroll
            for (int rr = 0; rr < 4; rr++) {
                int row = m0 + wm * 32 + i * 16 + q * 4 + rr;
                int col = n0 + wn * 32 + j * 16 + r;
                if (row < M && col < Nn) {
                    float v = acc[i][j][rr];
                    if (HAS_BIAS) v += bias[col];
                    C[(size_t)row * Nn + col] = v;
                }
            }
}

// ---------------- attention logits: el/er[n,h] = <feat[n,h,:], al/ar[h,:]> ----
__global__ void attn_k(const float* __restrict__ feat, const float* __restrict__ al,
                       const float* __restrict__ ar, float* __restrict__ el,
                       float* __restrict__ er) {
    int lane = threadIdx.x & 63;
    int wave = threadIdx.x >> 6;
    int node = blockIdx.x * 4 + wave;
    if (node >= NN) return;
    int h = lane >> 4;
    const float* fp = feat + (size_t)node * HF + lane * 8;
    float4 f0 = *(const float4*)fp;
    float4 f1 = *(const float4*)(fp + 4);
    const float* alp = al + h * 128 + (lane & 15) * 8;
    const float* arp = ar + h * 128 + (lane & 15) * 8;
    float fv[8] = {f0.x, f0.y, f0.z, f0.w, f1.x, f1.y, f1.z, f1.w};
    float sl = 0.f, sr = 0.f;
#pragma unroll
    for (int j = 0; j < 8; j++) {
        sl += fv[j] * alp[j];
        sr += fv[j] * arp[j];
    }
#pragma unroll
    for (int off = 8; off >= 1; off >>= 1) {
        sl += __shfl_down(sl, off, 16);
        sr += __shfl_down(sr, off, 16);
    }
    if ((lane & 15) == 0) {
        el[node * NHEAD + h] = sl;
        er[node * NHEAD + h] = sr;
    }
}

// ---------------- edge pass 1: logits + segment max ----------------
__global__ void edge_logit_k(const int* __restrict__ src, const int* __restrict__ dst,
                             const float* __restrict__ el, const float* __restrict__ er,
                             float* __restrict__ wbuf, unsigned* __restrict__ mbuf) {
    int tid = blockIdx.x * blockDim.x + threadIdx.x;
    if (tid >= NE * NHEAD) return;
    int e = tid >> 2, h = tid & 3;
    int d = dst[e];
    float lg = el[src[e] * NHEAD + h] + er[d * NHEAD + h];
    lg = lg > 0.f ? lg : 0.2f * lg;
    wbuf[tid] = lg;
    atomicMax(&mbuf[d * NHEAD + h], enc_f(lg));
}

// ---------------- edge pass 2: exp + segment sum ----------------
__global__ void edge_exp_k(const int* __restrict__ dst, float* __restrict__ wbuf,
                           const unsigned* __restrict__ mbuf, float* __restrict__ sbuf) {
    int tid = blockIdx.x * blockDim.x + threadIdx.x;
    if (tid >= NE * NHEAD) return;
    int e = tid >> 2, h = tid & 3;
    int d = dst[e];
    float m = dec_f(mbuf[d * NHEAD + h]);
    float v = __expf(wbuf[tid] - m);
    wbuf[tid] = v;
    atomicAdd(&sbuf[d * NHEAD + h], v);
}

// ---------------- scatter: acc[dst] += feat[src] * a ----------------
__global__ void scatter_k(const int* __restrict__ src, const int* __restrict__ dst,
                          const float* __restrict__ feat, const float* __restrict__ wbuf,
                          const float* __restrict__ sbuf, float* __restrict__ acc) {
    int lane = threadIdx.x & 63;
    int wave = threadIdx.x >> 6;
    int e = blockIdx.x * 4 + wave;
    if (e >= NE) return;
    int s = src[e], d = dst[e];
    int h = lane >> 4;
    float a = wbuf[e * NHEAD + h] / sbuf[d * NHEAD + h];
    const float* fp = feat + (size_t)s * HF + lane * 8;
    float* ap = acc + (size_t)d * HF + lane * 8;
    float4 f0 = *(const float4*)fp;
    float4 f1 = *(const float4*)(fp + 4);
    atomicAdd(ap + 0, f0.x * a);
    atomicAdd(ap + 1, f0.y * a);
    atomicAdd(ap + 2, f0.z * a);
    atomicAdd(ap + 3, f0.w * a);
    atomicAdd(ap + 4, f1.x * a);
    atomicAdd(ap + 5, f1.y * a);
    atomicAdd(ap + 6, f1.z * a);
    atomicAdd(ap + 7, f1.w * a);
}

// ---------------- per-type combine: hout (+)= bf16(leaky(acc + b_t)) ----------
__global__ void combine_k(const float* __restrict__ acc, const float* __restrict__ bt,
                          bf16* __restrict__ hout, int first, int act) {
    int i = blockIdx.x * blockDim.x + threadIdx.x;
    if (i >= NN * HF) return;
    int c = i & (HF - 1);
    float v = acc[i] + bt[c];
    if (act) v = v > 0.f ? v : 0.01f * v;
    if (!first) v += bf2f(hout[i]);
    hout[i] = __float2bfloat16(v);
}

extern "C" void kernel_launch(void* const* d_in, const int* in_sizes, int n_in,
                              void* d_out, int out_size, void* d_ws, size_t ws_size,
                              hipStream_t stream) {
    const float* x = (const float*)d_in[0];
    const int* srcs[2] = {(const int*)d_in[1], (const int*)d_in[3]};
    const int* dsts[2] = {(const int*)d_in[2], (const int*)d_in[4]};
    const float* W[3] = {(const float*)d_in[5], (const float*)d_in[9], (const float*)d_in[13]};
    const float* al[3] = {(const float*)d_in[6], (const float*)d_in[10], (const float*)d_in[14]};
    const float* ar[3] = {(const float*)d_in[7], (const float*)d_in[11], (const float*)d_in[15]};
    const float* bb[3] = {(const float*)d_in[8], (const float*)d_in[12], (const float*)d_in[16]};
    const float* Wout = (const float*)d_in[17];
    const float* bout = (const float*)d_in[18];

    // workspace layout (~172 MB)
    char* ws = (char*)d_ws;
    size_t off = 0;
    auto walloc = [&](size_t bytes) {
        void* p = ws + off;
        off = (off + bytes + 255) & ~(size_t)255;
        return p;
    };
    bf16* h0 = (bf16*)walloc((size_t)NN * HF * 2);
    bf16* h1 = (bf16*)walloc((size_t)NN * HF * 2);
    float* feat = (float*)walloc((size_t)NN * HF * 4);
    float* el = (float*)walloc((size_t)NN * NHEAD * 4);
    float* er = (float*)walloc((size_t)NN * NHEAD * 4);
    unsigned* mbuf = (unsigned*)walloc((size_t)NN * NHEAD * 4);
    float* sbuf = (float*)walloc((size_t)NN * NHEAD * 4);
    float* wbuf = (float*)walloc((size_t)NE * NHEAD * 4);
    bf16* WT = (bf16*)walloc((size_t)2983 * 512 * 2);

    // dead regions of d_out used as scratch (out is fp32, 477 MB;
    // final GEMM overwrites everything). acc: [0, 81.92MB), xb: [81.92, 163.84MB)
    float* acc = (float*)d_out;
    bf16* xb = (bf16*)((char*)d_out + (size_t)NN * HF * 4);

    const int EB = (NE * NHEAD + 255) / 256;  // edge-kernel blocks

    // cast x (fp32 -> bf16) once
    cast_k<<<(NN * 1024 / 4 + 255) / 256, 256, 0, stream>>>(x, xb, NN * 1024);

    for (int l = 0; l < 3; l++) {
        const int K = (l == 0) ? 1024 : 512;
        const bf16* hin = (l == 0) ? xb : ((l == 1) ? h0 : h1);
        bf16* hout = (l == 0) ? h0 : ((l == 1) ? h1 : h0);
        const int act = (l < 2) ? 1 : 0;
        for (int t = 0; t < 2; t++) {
            // feat = hin @ W[l][t]
            transpose_k<<<dim3(512 / 32, K / 32), dim3(32, 32), 0, stream>>>(
                W[l] + (size_t)t * K * 512, WT, K, 512);
            gemm_k<false><<<dim3(NN / 64, 512 / 64), 256, 0, stream>>>(
                hin, WT, feat, nullptr, NN, 512, K);
            // logits
            attn_k<<<NN / 4, 256, 0, stream>>>(feat, al[l] + t * HF, ar[l] + t * HF, el, er);
            // edge softmax
            hipMemsetAsync(mbuf, 0, (size_t)NN * NHEAD * 4, stream);
            hipMemsetAsync(sbuf, 0, (size_t)NN * NHEAD * 4, stream);
            edge_logit_k<<<EB, 256, 0, stream>>>(srcs[t], dsts[t], el, er, wbuf, mbuf);
            edge_exp_k<<<EB, 256, 0, stream>>>(dsts[t], wbuf, mbuf, sbuf);
            // aggregate
            hipMemsetAsync(acc, 0, (size_t)NN * HF * 4, stream);
            scatter_k<<<NE / 4, 256, 0, stream>>>(srcs[t], dsts[t], feat, wbuf, sbuf, acc);
            // per-type bias + activation, sum over types into hout (bf16)
            combine_k<<<(NN * HF + 255) / 256, 256, 0, stream>>>(
                acc, bb[l] + t * HF, hout, t == 0 ? 1 : 0, act);
        }
    }

    // final projection: out = h @ Wout + bout   [40000 x 2983] fp32
    transpose_k<<<dim3((2983 + 31) / 32, 512 / 32), dim3(32, 32), 0, stream>>>(
        Wout, WT, 512, 2983);
    gemm_k<true><<<dim3(NN / 64, (2983 + 63) / 64), 256, 0, stream>>>(
        h0, WT, (float*)d_out, bout, NN, 2983, 512);
}